// Round 7
// baseline (673.422 us; speedup 1.0000x reference)
//
#include <hip/hip_runtime.h>
#include <stdint.h>

typedef __attribute__((ext_vector_type(8))) __bf16 bf16x8;
typedef __attribute__((ext_vector_type(4))) float  f32x4;

// ---------- helpers ----------
__device__ __forceinline__ uint16_t f2b(float f) {           // fp32 -> bf16 RNE
  uint32_t u = __float_as_uint(f);
  u += 0x7fffu + ((u >> 16) & 1u);
  return (uint16_t)(u >> 16);
}
__device__ __forceinline__ float b2f_lo(uint32_t p) { return __uint_as_float(p << 16); }
__device__ __forceinline__ float b2f_hi(uint32_t p) { return __uint_as_float(p & 0xffff0000u); }

// branch-free tanh: 1 - 2/(e^{2x}+1); saturates correctly at +-1
__device__ __forceinline__ float tanh_fast(float x) {
  float e = __expf(2.0f * x);
  return 1.0f - 2.0f / (e + 1.0f);
}

// barrier draining ONLY lgkmcnt (ds ops) — global prefetch stays in flight.
__device__ __forceinline__ void barrier_lgkm() {
  asm volatile("s_waitcnt lgkmcnt(0)\n\ts_barrier" ::: "memory");
}

// ---------- 1. mega-prep: ALL setup in one dispatch (R5 lesson: ~35-45 us per
// dispatch of launch/gap overhead dominates the residue; collapse the chain).
// Roles by blockIdx (short roles FIRST so they hide under the BW-bound convert):
//   [0,32)        u[b,:] = dec_last[b,:] @ U_a   (direct, no atomics, no memset)
//   [32,288)      W_a -> WT bf16 transpose (LDS-tiled)
//   [288,320)     zero ctx (plain stores, replaces hipMemsetAsync)
//   [320,33088)   encoder fp32 -> bf16 (8 elems/thread), i.e. old convert_enc
__global__ __launch_bounds__(256) void prep(const float4* __restrict__ enc4,
                                            uint4* __restrict__ encA4,
                                            const float* __restrict__ W,
                                            uint16_t* __restrict__ WT,
                                            const float* __restrict__ dec,
                                            const float4* __restrict__ U4,
                                            float* __restrict__ u,
                                            float* __restrict__ ctx) {
  __shared__ float tile[64][65];
  const int bx = blockIdx.x;
  const int tid = threadIdx.x;
  if (bx < 32) {
    // ---- u role: one block per batch; each thread owns 4 f-cols, full K loop.
    // U (4 MB) is read by 4 blocks per XCD -> L2-resident after first touch.
    int b = bx;
    float* sdec = &tile[0][0];  // 1024 floats
    ((float4*)sdec)[tid] = *((const float4*)(dec + (size_t)b * 65536 + 64512) + tid);
    __syncthreads();
    float4 a = {0.f, 0.f, 0.f, 0.f};
    const float4* Ub = U4 + tid;
    #pragma unroll 4
    for (int d = 0; d < 1024; ++d) {
      float4 w = Ub[(size_t)d * 256];
      float s = sdec[d];
      a.x = fmaf(s, w.x, a.x);
      a.y = fmaf(s, w.y, a.y);
      a.z = fmaf(s, w.z, a.z);
      a.w = fmaf(s, w.w, a.w);
    }
    *(float4*)(u + b * 1024 + tid * 4) = a;
  } else if (bx < 288) {
    // ---- WT role: W_a (K x N) -> WT bf16 (N x K), LDS-tiled transpose ----
    int bxl = bx - 32;
    int k0 = (bxl & 15) * 64;
    int n0 = (bxl >> 4) * 64;
    #pragma unroll
    for (int it = 0; it < 16; ++it) {
      int idx = it * 256 + tid;
      int kr = idx >> 6, nc = idx & 63;
      tile[kr][nc] = W[(size_t)(k0 + kr) * 1024 + n0 + nc];
    }
    __syncthreads();
    #pragma unroll
    for (int it = 0; it < 16; ++it) {
      int idx = it * 256 + tid;
      int nr = idx >> 6, kc = idx & 63;
      WT[(size_t)(n0 + nr) * 1024 + k0 + kc] = f2b(tile[kc][nr]);
    }
  } else if (bx < 320) {
    // ---- zero-ctx role ----
    float4 z = {0.f, 0.f, 0.f, 0.f};
    *(float4*)(ctx + (size_t)((bx - 288) * 256 + tid) * 4) = z;
  } else {
    // ---- convert role: encoder fp32 -> bf16, 8 elems/thread ----
    int i = (bx - 320) * 256 + tid;
    float4 a = enc4[2 * i], b = enc4[2 * i + 1];
    uint4 o;
    o.x = (uint32_t)f2b(a.x) | ((uint32_t)f2b(a.y) << 16);
    o.y = (uint32_t)f2b(a.z) | ((uint32_t)f2b(a.w) << 16);
    o.z = (uint32_t)f2b(b.x) | ((uint32_t)f2b(b.y) << 16);
    o.w = (uint32_t)f2b(b.z) | ((uint32_t)f2b(b.w) << 16);
    encA4[i] = o;
  }
}

// ---------- 2. fused GEMM (R0-proven structure, byte-identical): bf16 A from
// encA, 128x128 tile, 4 waves, BK=32, LDS double-buffer, lgkm-only barriers,
// named prefetch regs, XOR-swizzled fragment-order LDS slots (0 conflicts).
__global__ __launch_bounds__(256, 3) void gemm_score(const uint16_t* __restrict__ A,
                                                     const uint16_t* __restrict__ BT,
                                                     const float* __restrict__ u,
                                                     const float* __restrict__ v,
                                                     float* __restrict__ spart) {
  __shared__ uint4 sAB[2][1024];  // [buf][ A slots 0..511 | B slots 512..1023 ]
  __shared__ float sred[128];

  int bx = blockIdx.x;
  int g = bx >> 6, r = bx & 63;
  int mtile = g * 8 + (r & 7);
  int ntile = r >> 3;

  int tid = threadIdx.x;
  int lane = tid & 63;
  int wid  = tid >> 6;
  int wm = (wid & 1) * 64;
  int wn = (wid >> 1) * 64;
  int quad = lane >> 4, nib = lane & 15;
  const int lsw = lane ^ ((lane >> 4) << 1);  // swizzled read lane

  f32x4 acc[4][4];
  #pragma unroll
  for (int i = 0; i < 4; ++i)
    #pragma unroll
    for (int j = 0; j < 4; ++j) acc[i][j] = (f32x4){0.f, 0.f, 0.f, 0.f};

  const int rowA = mtile * 128;
  const int rowB = ntile * 128;
  const int c0 = tid, c1 = tid + 256;            // global-order chunks
  const uint4* pA0 = (const uint4*)(A  + (size_t)(rowA + (c0 >> 2)) * 1024 + (c0 & 3) * 8);
  const uint4* pA1 = (const uint4*)(A  + (size_t)(rowA + (c1 >> 2)) * 1024 + (c1 & 3) * 8);
  const uint4* pB0 = (const uint4*)(BT + (size_t)(rowB + (c0 >> 2)) * 1024 + (c0 & 3) * 8);
  const uint4* pB1 = (const uint4*)(BT + (size_t)(rowB + (c1 >> 2)) * 1024 + (c1 & 3) * 8);
  // fragment-order LDS slots, XOR-swizzled by kc (kc = c&3, same for c0,c1)
  const int s0 = (((c0 >> 6) << 6) | ((c0 & 3) << 4) | ((c0 >> 2) & 15)) ^ ((c0 & 3) << 1);
  const int s1 = (((c1 >> 6) << 6) | ((c1 & 3) << 4) | ((c1 >> 2) & 15)) ^ ((c1 & 3) << 1);

  // named prefetch sets (NO arrays): set-a holds even iters, set-b odd iters
  uint4 A0a, A1a, B0a, B1a, A0b, A1b, B0b, B1b;

#define GEMM_STEP(BUF)                                                          \
  do {                                                                          \
    bf16x8 af[4], bf[4];                                                        \
    _Pragma("unroll")                                                           \
    for (int i = 0; i < 4; ++i)                                                 \
      af[i] = *(const bf16x8*)&sAB[BUF][((wm >> 4) + i) * 64 + lsw];            \
    _Pragma("unroll")                                                           \
    for (int j = 0; j < 4; ++j)                                                 \
      bf[j] = *(const bf16x8*)&sAB[BUF][512 + ((wn >> 4) + j) * 64 + lsw];      \
    _Pragma("unroll")                                                           \
    for (int i = 0; i < 4; ++i)                                                 \
      _Pragma("unroll")                                                         \
      for (int j = 0; j < 4; ++j)                                               \
        acc[i][j] = __builtin_amdgcn_mfma_f32_16x16x32_bf16(af[i], bf[j],       \
                                                            acc[i][j], 0, 0, 0);\
  } while (0)

  // preamble: k=0 -> set-a, k=1 -> set-b; stage k=0 into buf0
  A0a = pA0[0]; A1a = pA1[0]; B0a = pB0[0]; B1a = pB1[0];
  A0b = pA0[4]; A1b = pA1[4]; B0b = pB0[4]; B1b = pB1[4];
  sAB[0][s0] = A0a; sAB[0][s1] = A1a;
  sAB[0][512 + s0] = B0a; sAB[0][512 + s1] = B1a;
  barrier_lgkm();

  for (int k = 0; k < 32; k += 2) {
    // ---- even body: compute from buf0; set-a free (staged last odd body)
    if (k < 30) {
      A0a = pA0[(k + 2) * 4]; A1a = pA1[(k + 2) * 4];
      B0a = pB0[(k + 2) * 4]; B1a = pB1[(k + 2) * 4];
    }
    GEMM_STEP(0);
    // stage iter k+1 (set-b) into buf1
    sAB[1][s0] = A0b; sAB[1][s1] = A1b;
    sAB[1][512 + s0] = B0b; sAB[1][512 + s1] = B1b;
    barrier_lgkm();

    // ---- odd body: compute from buf1; set-b free
    if (k < 29) {
      A0b = pA0[(k + 3) * 4]; A1b = pA1[(k + 3) * 4];
      B0b = pB0[(k + 3) * 4]; B1b = pB1[(k + 3) * 4];
    }
    GEMM_STEP(1);
    if (k < 30) {  // stage iter k+2 (set-a) into buf0
      sAB[0][s0] = A0a; sAB[0][s1] = A1a;
      sAB[0][512 + s0] = B0a; sAB[0][512 + s1] = B1a;
    }
    barrier_lgkm();
  }
#undef GEMM_STEP

  // ---- epilogue ----
  int b = rowA >> 11;  // 128 | 2048 so batch is block-uniform
  float vv[4], uu[4];
  #pragma unroll
  for (int j = 0; j < 4; ++j) {
    int col = ntile * 128 + wn + j * 16 + nib;
    vv[j] = v[col];
    uu[j] = u[b * 1024 + col];
  }
  float sloc[4][4];
  #pragma unroll
  for (int i = 0; i < 4; ++i) {
    #pragma unroll
    for (int reg = 0; reg < 4; ++reg) {
      float s = 0.f;
      #pragma unroll
      for (int j = 0; j < 4; ++j) s += vv[j] * tanh_fast(acc[i][j][reg] + uu[j]);
      s += __shfl_xor(s, 1);
      s += __shfl_xor(s, 2);
      s += __shfl_xor(s, 4);
      s += __shfl_xor(s, 8);
      sloc[i][reg] = s;  // row = wm + i*16 + quad*4 + reg, cols wn..wn+63
    }
  }
  if (wid < 2 && nib == 0) {  // col-half 0 deposits
    #pragma unroll
    for (int i = 0; i < 4; ++i)
      #pragma unroll
      for (int reg = 0; reg < 4; ++reg)
        sred[wm + i * 16 + quad * 4 + reg] = sloc[i][reg];
  }
  __syncthreads();
  if (wid >= 2 && nib == 0) {  // col-half 1 combines + stores
    float* outp = spart + (size_t)ntile * 65536 + rowA;
    #pragma unroll
    for (int i = 0; i < 4; ++i) {
      int rloc = wm + i * 16 + quad * 4;
      float4 sv;
      #pragma unroll
      for (int reg = 0; reg < 4; ++reg)
        ((float*)&sv)[reg] = sloc[i][reg] + sred[rloc + reg];
      *(float4*)(outp + rloc) = sv;
    }
  }
}

// ---------- 3. fused softmax + context: one dispatch. Each (b, 128-t chunk)
// block recomputes the softmax for batch b (cheap: 16K L2-hot spart reads),
// keeps w in LDS; ch==0 blocks write the wts output; all blocks then do their
// context chunk over bf16 encA and atomicAdd into ctx (zeroed by prep).
__global__ __launch_bounds__(256) void ctx_softmax(const float* __restrict__ spart,
                                                   const uint16_t* __restrict__ encA,
                                                   float* __restrict__ wts,
                                                   float* __restrict__ ctx) {
  int b = blockIdx.x >> 4, ch = blockIdx.x & 15;
  int tid = threadIdx.x;
  __shared__ float lw[2048];
  __shared__ float sctx[1024];
  __shared__ float red[4];

  // ---- softmax recompute over all t (global denominators) ----
  float sv[8];
  float mx = -1e30f;
  #pragma unroll
  for (int i = 0; i < 8; ++i) {
    int idx = b * 2048 + i * 256 + tid;
    float s = 0.f;
    #pragma unroll
    for (int j = 0; j < 8; ++j) s += spart[j * 65536 + idx];
    sv[i] = s;
    mx = fmaxf(mx, s);
  }
  #pragma unroll
  for (int off = 1; off < 64; off <<= 1) mx = fmaxf(mx, __shfl_xor(mx, off));
  if ((tid & 63) == 0) red[tid >> 6] = mx;
  __syncthreads();
  mx = fmaxf(fmaxf(red[0], red[1]), fmaxf(red[2], red[3]));
  __syncthreads();
  float sum = 0.f;
  #pragma unroll
  for (int i = 0; i < 8; ++i) {
    sv[i] = __expf(sv[i] - mx);
    sum += sv[i];
  }
  #pragma unroll
  for (int off = 1; off < 64; off <<= 1) sum += __shfl_xor(sum, off);
  if ((tid & 63) == 0) red[tid >> 6] = sum;
  __syncthreads();
  float inv = 1.0f / (red[0] + red[1] + red[2] + red[3]);
  #pragma unroll
  for (int i = 0; i < 8; ++i) {
    float wv = sv[i] * inv;
    lw[i * 256 + tid] = wv;
    if (ch == 0) wts[b * 2048 + i * 256 + tid] = wv;
  }
  __syncthreads();

  // ---- context chunk: t in [ch*128, ch*128+128), split in 2 t-halves ----
  int th = tid >> 7;   // t-half
  int ig = tid & 127;  // elem group (8 elems)
  int e0 = ig * 8;
  float a[8] = {0.f, 0.f, 0.f, 0.f, 0.f, 0.f, 0.f, 0.f};
  const uint16_t* base = encA + (size_t)b * 2048 * 1024 +
                         (size_t)(ch * 128 + th * 64) * 1024 + e0;
  const float* lwp = lw + ch * 128 + th * 64;
  #pragma unroll 2
  for (int t = 0; t < 64; ++t) {
    uint4 p = *(const uint4*)(base + (size_t)t * 1024);
    float wt = lwp[t];
    a[0] = fmaf(wt, b2f_lo(p.x), a[0]);
    a[1] = fmaf(wt, b2f_hi(p.x), a[1]);
    a[2] = fmaf(wt, b2f_lo(p.y), a[2]);
    a[3] = fmaf(wt, b2f_hi(p.y), a[3]);
    a[4] = fmaf(wt, b2f_lo(p.z), a[4]);
    a[5] = fmaf(wt, b2f_hi(p.z), a[5]);
    a[6] = fmaf(wt, b2f_lo(p.w), a[6]);
    a[7] = fmaf(wt, b2f_hi(p.w), a[7]);
  }
  if (th == 0) {
    #pragma unroll
    for (int k = 0; k < 8; ++k) sctx[e0 + k] = a[k];
  }
  __syncthreads();
  if (th == 1) {
    float* cp = ctx + b * 1024 + e0;
    #pragma unroll
    for (int k = 0; k < 8; ++k) atomicAdd(cp + k, a[k] + sctx[e0 + k]);
  }
}

extern "C" void kernel_launch(void* const* d_in, const int* in_sizes, int n_in,
                              void* d_out, int out_size, void* d_ws, size_t ws_size,
                              hipStream_t stream) {
  const float* enc = (const float*)d_in[0];  // (32, 2048, 1024)
  const float* dec = (const float*)d_in[1];  // (32, 64, 1024)
  const float* Wa  = (const float*)d_in[2];  // (1024, 1024)
  const float* Ua  = (const float*)d_in[3];  // (1024, 1024)
  const float* Va  = (const float*)d_in[4];  // (1024, 1)

  float* out = (float*)d_out;
  float* ctx = out;                 // 32*1024
  float* wts = out + 32 * 1024;     // 32*2048*1

  char* ws = (char*)d_ws;
  uint16_t* encA  = (uint16_t*)ws;                           // 128 MB bf16 encoder
  uint16_t* WT    = (uint16_t*)(ws + 134217728);             // 2 MB bf16 W^T
  float*    ub    = (float*)  (ws + 136314880);              // 128 KB u[b,f]
  float*    spart = (float*)  (ws + 136445952);              // 2 MB score partials [8][65536]

  prep<<<33088, 256, 0, stream>>>((const float4*)enc, (uint4*)encA, Wa, WT,
                                  dec, (const float4*)Ua, ub, ctx);
  gemm_score<<<4096, 256, 0, stream>>>(encA, WT, ub, Va, spart);
  ctx_softmax<<<512, 256, 0, stream>>>(spart, encA, wts, ctx);
}